// Round 6
// baseline (193.023 us; speedup 1.0000x reference)
//
#include <hip/hip_runtime.h>
#include <math.h>

// Problem constants (fixed): B=4, C=256, H=64, W=128, D=4, 81 shifts, C/R=16
// out: [B, 81, H, W] fp32 (2,654,208 elements)
// ws (floats): [0) pooled 82,944  [82944) At 82,944  [165888) cpart 2,654,208

#define HH 64
#define WW 128
#define CC 256
#define BB 4

// ---------------------------------------------------------------------------
// Kernel A: pooled[b, s, c] = sum_{h,w} f1[b,c,h,w] * f2pad[b,c,h+i,w+j]
// One 576-thread block (9 waves) per (b,c) plane; thread (h=t/9, di=t%9)
// owns a full row. UNCHANGED.
// ---------------------------------------------------------------------------
__global__ __launch_bounds__(576) void corr_pool_kernel(
    const float* __restrict__ f1, const float* __restrict__ f2,
    float* __restrict__ pooled) {
  const int t  = threadIdx.x;
  const int bc = blockIdx.x;                    // b*256 + c
  const float* f1p = f1 + (size_t)bc * (HH * WW);
  const float* f2p = f2 + (size_t)bc * (HH * WW);

  __shared__ float4 f2s4[72 * 35];              // 40,320 B; reused for reduce

  // --- stage f2 plane with zero halo (single barrier) ---
  const float4 z4 = make_float4(0.f, 0.f, 0.f, 0.f);
  for (int u = t; u < 72 * 35; u += 576) {
    const int rl = u / 35, k = u - rl * 35;     // padded row, padded chunk
    const int gr = rl - 4;                      // f2 row
    float4 v = z4;
    if ((unsigned)gr < 64u && k >= 1 && k <= 32)
      v = *(const float4*)(f2p + (gr << 7) + ((k - 1) << 2));
    f2s4[u] = v;
  }
  __syncthreads();

  // --- stage 1: thread (h, di) accumulates s9[j] over its full row ---
  const int h  = t / 9;                         // 0..63
  const int di = t - h * 9;                     // 0..8
  const float4* f2row = &f2s4[(h + di) * 35];   // padded row h+di
  const float* f1row  = f1p + (h << 7);

  float s9[9];
#pragma unroll
  for (int j = 0; j < 9; ++j) s9[j] = 0.f;

  alignas(16) float f1c[16], f2wc[24];
#pragma unroll
  for (int m = 0; m < 4; ++m)
    *(float4*)&f1c[4 * m] = *(const float4*)(f1row + (m << 2));
#pragma unroll
  for (int m = 0; m < 6; ++m) *(float4*)&f2wc[4 * m] = f2row[m];

  for (int seg = 0; seg < 8; ++seg) {
    const int nxt = (seg < 7) ? seg + 1 : 7;    // clamped (dup load on last)
    alignas(16) float f1n[16], f2wn[24];
#pragma unroll
    for (int m = 0; m < 4; ++m)
      *(float4*)&f1n[4 * m] =
          *(const float4*)(f1row + (nxt << 4) + (m << 2));
#pragma unroll
    for (int m = 0; m < 6; ++m) *(float4*)&f2wn[4 * m] = f2row[(nxt << 2) + m];

#pragma unroll
    for (int k = 0; k < 16; ++k) {
      const float a = f1c[k];
#pragma unroll
      for (int j = 0; j < 9; ++j) s9[j] += a * f2wc[k + j];
    }
#pragma unroll
    for (int m = 0; m < 16; ++m) f1c[m] = f1n[m];
#pragma unroll
    for (int m = 0; m < 24; ++m) f2wc[m] = f2wn[m];
  }

  // --- stage 2: parallel column reduction (all 576 threads) ---
  __syncthreads();                              // stage-1 LDS reads done
  float* red  = (float*)f2s4;                   // [64][81]
  float* red2 = red + 64 * 81;                  // [7][81]
#pragma unroll
  for (int j = 0; j < 9; ++j) red[h * 81 + di * 9 + j] = s9[j];
  __syncthreads();

  if (t < 567) {                                // 7 groups x 81 cols
    const int col = t % 81, g = t / 81;
    const int r0 = g * 9, r1 = (g == 6) ? 64 : r0 + 9;
    float acc = 0.f;
#pragma unroll 3
    for (int rr = r0; rr < r1; ++rr) acc += red[rr * 81 + col];
    red2[g * 81 + col] = acc;
  }
  __syncthreads();

  if (t < 81) {
    float acc = 0.f;
#pragma unroll
    for (int g = 0; g < 7; ++g) acc += red2[g * 81 + t];
    const int b = bc >> 8, c = bc & 255;
    pooled[(size_t)(b * 81 + t) * 256 + c] = acc;   // raw sum (/8192 in B)
  }
}

// ---------------------------------------------------------------------------
// Kernel B: At[b, c, s] = sigmoid(MLP(pooled/8192)). Transposed output for
// kernel C's wave-uniform coefficient s_loads. UNCHANGED.
// ---------------------------------------------------------------------------
__global__ __launch_bounds__(256) void mlp_kernel(
    const float* __restrict__ pooled, const float* __restrict__ w1,
    const float* __restrict__ b1, const float* __restrict__ w2,
    const float* __restrict__ b2, float* __restrict__ At) {
  const int bs = blockIdx.x;                    // b*81 + s
  const int t  = threadIdx.x;
  const int b  = bs / 81;
  const int s  = bs - b * 81;
  __shared__ float p[256];
  __shared__ float hid[16];

  p[t] = pooled[(size_t)bs * 256 + t] * (1.0f / 8192.0f);
  __syncthreads();

  const int g = t >> 4, ln = t & 15;
  float acc = 0.f;
#pragma unroll
  for (int m = 0; m < 16; ++m) {
    const int c = (m << 4) + ln;
    acc += w1[(g << 8) + c] * p[c];
  }
  acc += __shfl_xor(acc, 1);
  acc += __shfl_xor(acc, 2);
  acc += __shfl_xor(acc, 4);
  acc += __shfl_xor(acc, 8);
  if (ln == 0) hid[g] = acc + b1[g];
  __syncthreads();

  float acc2 = b2[t];
#pragma unroll
  for (int k = 0; k < 16; ++k) acc2 += w2[(t << 4) + k] * hid[k];
  const float sv = 1.0f / (1.0f + __expf(-acc2));
  At[((size_t)(b * 256 + t)) * 81 + s] = sv;    // transposed: [b][c][81]
}

// ---------------------------------------------------------------------------
// Async 16B global->LDS copy: lane l's 16B lands at ldsbase + l*16.
// Per-lane exec mask applies (predicated lanes don't write).
// ---------------------------------------------------------------------------
__device__ __forceinline__ void async16(const float* g, void* lds) {
  __builtin_amdgcn_global_load_lds(
      (const __attribute__((address_space(1))) void*)g,
      (__attribute__((address_space(3))) void*)lds, 16, 0, 0);
}

// ---------------------------------------------------------------------------
// Kernel C: channel-half partial of
//   out[b, i*9+j, h, w] = (1/256) sum_c At[b,c,i*9+j]*f1[c,h,w]*f2[c,h+i-4,w+j-4]
// Round-15: RESUBMIT of round-14 (container failed twice, no GPU output;
// audit found no hang/fault mechanism -- all barriers unconditional, halo
// validity wave-uniform by pair alignment, buffer race excluded by the
// vmcnt-draining barrier, addresses in bounds). Theory unchanged:
// per-CU L1 miss-path (MSHR x latency) limits ~64us; one 9-wave block per
// (b, row-pair, channel-half) stages f1(2 rows)+f2(10 halo rows) per channel
// ONCE into LDS; all 9 waves (one i each, 9 j's) consume the shared tile.
// Per-CU unique misses drop 3x (2.3 -> 0.77 MB). Stage(k+1) issued BEFORE
// compute(k); end-of-iter __syncthreads drains it after ~800cy FMA cover.
// Out-of-range halo rows: LDS pre-zeroed, stage lanes predicated off.
// Success: dur 22-32us, FETCH ~65-72MB, VALUBusy 55-75%. Fail (flat ~60):
// miss-bandwidth theory wrong -> MFMA rewrite next.
// ---------------------------------------------------------------------------
__global__ __launch_bounds__(576) void out_kernel(
    const float* __restrict__ f1, const float* __restrict__ f2,
    const float* __restrict__ At, float* __restrict__ out,
    float* __restrict__ part) {
  // bijective XCD swizzle: 256 blocks, XCD k gets work k*32..k*32+31
  const int bid  = blockIdx.x;
  const int work = (bid & 7) * 32 + (bid >> 3);
  const int rt   = work & 31;                   // row-pair tile
  const int half = (work >> 5) & 1;             // channel half
  const int b    = work >> 6;
  const int h0   = rt << 1;

  const int t    = threadIdx.x;
  const int wv   = t >> 6;                      // wave = i shift, 0..8
  const int lane = t & 63;
  const int r    = lane >> 5;                   // 0..1 (row within pair)
  const int cidx = lane & 31;                   // float4 column
  const int w0   = cidx << 2;
  const int h    = h0 + r;
  const int iu   = __builtin_amdgcn_readfirstlane(wv);  // SGPR i

  // [buf][ch-of-pair][row: 0..9 f2 halo, 10..11 f1][col] -- 24,576 B
  __shared__ float4 st[2][2][12][32];

  const int c0 = half << 7;
  const float* f1pl = f1 + ((size_t)b * 256 + c0) * 8192;
  const float* f2pl = f2 + ((size_t)b * 256 + c0) * 8192;
  const float* Aa   = At + ((size_t)(b * 256 + c0)) * 81 + iu * 9;

  // --- stage unit assignment: 12 units = 2ch x (5 f2 row-pairs + 1 f1) ---
  // unit A: wave w -> ch (w>=6), slot w-6*(w>=6). unit B (w<3): ch 1, slot w+3.
  const int chA   = (wv >= 6) ? 1 : 0;
  const int slotA = wv - 6 * chA;               // 0..5
  const bool isF1A = (slotA == 5);
  const int rowA  = h0 - 4 + 2 * slotA + (lane >> 5);
  const bool validA = isF1A || ((unsigned)rowA < 64u);
  const float* gA = (isF1A ? f1pl + h0 * 128
                           : f2pl + (h0 - 4 + 2 * slotA) * 128)
                    + (size_t)chA * 8192 + lane * 4;

  const int slotB = ((wv < 3) ? wv : 0) + 3;    // 3..5 (clamped for wv>=3)
  const bool isF1B = (slotB == 5);
  const int rowB  = h0 - 4 + 2 * slotB + (lane >> 5);
  const bool validB = isF1B || ((unsigned)rowB < 64u);
  const float* gB = (isF1B ? f1pl + h0 * 128
                           : f2pl + (h0 - 4 + 2 * slotB) * 128)
                    + (size_t)8192 + lane * 4;  // ch 1

  // --- pre-zero both buffers (covers never-staged invalid halo rows) ---
  {
    const float4 z4 = make_float4(0.f, 0.f, 0.f, 0.f);
    float4* stf = &st[0][0][0][0];
    for (int u = t; u < 2 * 2 * 12 * 32; u += 576) stf[u] = z4;
  }
  __syncthreads();

  // --- prologue: stage channel pair k=0 (c0+0, c0+1) into buf 0 ---
  if (validA) async16(gA, &st[0][chA][2 * slotA][0]);
  if (wv < 3 && validB) async16(gB, &st[0][1][2 * slotB][0]);
  __syncthreads();                              // drains asyncs

  float acc[9][4];
#pragma unroll
  for (int j = 0; j < 9; ++j)
#pragma unroll
    for (int k = 0; k < 4; ++k) acc[j][k] = 0.f;

  const bool vA = (cidx > 0);
  const bool vC = (cidx < 31);
  const int cxm1 = vA ? cidx - 1 : cidx;
  const int cxp1 = vC ? cidx + 1 : cidx;
  const int riu  = r + iu;                      // LDS f2 row for this wave

  for (int k = 0; k < 64; ++k) {
    const int cur = k & 1, nxt = cur ^ 1;

    // --- issue stage for pair k+1 (dup of k=63 at the end, never read) ---
    const int adv = (k < 63) ? 16384 : 0;       // 2 channels
    gA += adv; gB += adv;
    if (validA) async16(gA, &st[nxt][chA][2 * slotA][0]);
    if (wv < 3 && validB) async16(gB, &st[nxt][1][2 * slotB][0]);

    // --- consume channel pair (2k, 2k+1) from st[cur] ---
    const float* ca = Aa + (size_t)(2 * k) * 81;  // wave-uniform -> s_load
#pragma unroll
    for (int sub = 0; sub < 2; ++sub) {
      const float* cf = ca + sub * 81;
      const float4 x4 = st[cur][sub][10 + r][cidx];
      const float4 A4 = st[cur][sub][riu][cxm1];
      const float4 B4 = st[cur][sub][riu][cidx];
      const float4 C4 = st[cur][sub][riu][cxp1];

      alignas(16) float f2r[12];
      f2r[0]  = vA ? A4.x : 0.f;
      f2r[1]  = vA ? A4.y : 0.f;
      f2r[2]  = vA ? A4.z : 0.f;
      f2r[3]  = vA ? A4.w : 0.f;
      f2r[4]  = B4.x; f2r[5] = B4.y; f2r[6] = B4.z; f2r[7] = B4.w;
      f2r[8]  = vC ? C4.x : 0.f;
      f2r[9]  = vC ? C4.y : 0.f;
      f2r[10] = vC ? C4.z : 0.f;
      f2r[11] = vC ? C4.w : 0.f;
      alignas(16) const float xx[4] = {x4.x, x4.y, x4.z, x4.w};

#pragma unroll
      for (int j = 0; j < 9; ++j) {
        const float wj = cf[j];
#pragma unroll
        for (int kk = 0; kk < 4; ++kk)
          acc[j][kk] += wj * (xx[kk] * f2r[kk + j]);
      }
    }

    __syncthreads();                            // drains stage(k+1), syncs
  }

  // --- epilogue: wave i writes its 9 j-planes, 2 rows x 128 px ---
  float* dst = half ? part : out;
  const float inv = 1.0f / 256.0f;
#pragma unroll
  for (int j = 0; j < 9; ++j) {
    float4 o;
    o.x = acc[j][0] * inv;
    o.y = acc[j][1] * inv;
    o.z = acc[j][2] * inv;
    o.w = acc[j][3] * inv;
    *(float4*)(dst + (((size_t)(b * 81 + iu * 9 + j) * 64 + h) << 7) + w0) = o;
  }
}

// ---------------------------------------------------------------------------
// Combine: out += channel-half-1 partial. 663,552 float4s, grid 2592 x 256.
// ---------------------------------------------------------------------------
__global__ __launch_bounds__(256) void combine_kernel(
    float* __restrict__ out, const float* __restrict__ part) {
  const size_t idx = (size_t)blockIdx.x * 256 + threadIdx.x;  // float4 index
  float4* o4       = (float4*)out;
  const float4* p4 = (const float4*)part;
  const float4 a = o4[idx], p = p4[idx];
  float4 rv;
  rv.x = a.x + p.x; rv.y = a.y + p.y; rv.z = a.z + p.z; rv.w = a.w + p.w;
  o4[idx] = rv;
}

// ---------------------------------------------------------------------------
extern "C" void kernel_launch(void* const* d_in, const int* in_sizes, int n_in,
                              void* d_out, int out_size, void* d_ws, size_t ws_size,
                              hipStream_t stream) {
  const float* feat1 = (const float*)d_in[0];
  const float* feat2 = (const float*)d_in[1];
  const float* w1    = (const float*)d_in[2];
  const float* b1    = (const float*)d_in[3];
  const float* w2    = (const float*)d_in[4];
  const float* b2    = (const float*)d_in[5];
  float* out = (float*)d_out;

  float* pooled = (float*)d_ws;                 // 82,944 floats
  float* At     = pooled + 82944;               // 82,944 floats
  float* cpart  = At + 82944;                   // 2,654,208 floats

  corr_pool_kernel<<<1024, 576, 0, stream>>>(feat1, feat2, pooled);
  mlp_kernel<<<4 * 81, 256, 0, stream>>>(pooled, w1, b1, w2, b2, At);
  out_kernel<<<256, 576, 0, stream>>>(feat1, feat2, At, out, cpart);
  combine_kernel<<<2592, 256, 0, stream>>>(out, cpart);
}